// Round 7
// baseline (81.192 us; speedup 1.0000x reference)
//
#include <hip/hip_runtime.h>

typedef __bf16 bf16x8 __attribute__((ext_vector_type(8)));
typedef float  f32x4  __attribute__((ext_vector_type(4)));

__device__ __forceinline__ unsigned short f2bf(float f) {
  unsigned u = __float_as_uint(f);
  u = u + 0x7fffu + ((u >> 16) & 1u);   // RNE
  return (unsigned short)(u >> 16);
}
__device__ __forceinline__ float bf2f(unsigned short h) {
  return __uint_as_float(((unsigned)h) << 16);
}

// K0: convert x (f32) -> xb (bf16), 8 elems/thread
__global__ __launch_bounds__(256) void cvt_bf16(
    const float* __restrict__ x, unsigned short* __restrict__ xb, int total8) {
  int i = blockIdx.x * 256 + threadIdx.x;
  if (i >= total8) return;
  const float4* p = (const float4*)(x + (size_t)i * 8);
  float4 a = p[0], b = p[1];
  union { unsigned short u[8]; uint4 v; } r;
  r.u[0] = f2bf(a.x); r.u[1] = f2bf(a.y); r.u[2] = f2bf(a.z); r.u[3] = f2bf(a.w);
  r.u[4] = f2bf(b.x); r.u[5] = f2bf(b.y); r.u[6] = f2bf(b.z); r.u[7] = f2bf(b.w);
  ((uint4*)xb)[i] = r.v;
}

// K1: mean aggregation. 1 node per wave, lane = feature.
// One 64-wide load fetches indices for up to 64 edges (covers ~98% of nodes
// in a single index trip); v_readlane distributes them to SGPR gather bases.
// Gathers stream through ping-pong gA/gB 16-reg buffers -> up to 32 loads in
// flight, no dependent index trip between batches.
template <bool BF, bool AGGBF>
__global__ __launch_bounds__(256) void agg_k(
    const float* __restrict__ x, const unsigned short* __restrict__ xb,
    const int* __restrict__ row, const int* __restrict__ colptr,
    float* __restrict__ aggf, unsigned short* __restrict__ aggb, int N) {
  int wid  = blockIdx.x * 4 + (threadIdx.x >> 6);
  int lane = threadIdx.x & 63;
  if (wid >= N) return;
  int s = __builtin_amdgcn_readfirstlane(colptr[wid]);
  int e = __builtin_amdgcn_readfirstlane(colptr[wid + 1]);
  float acc = 0.0f;

#define ISSUE16(G, BASE)                                                     \
  {                                                                          \
    _Pragma("unroll")                                                        \
    for (int j = 0; j < 16; ++j) {                                           \
      int ij = __builtin_amdgcn_readlane(idxv, (BASE) + j);                  \
      G[j] = BF ? bf2f(xb[(size_t)ij * 64 + lane])                           \
                : x[(size_t)ij * 64 + lane];                                 \
    }                                                                        \
  }
#define CONSUME16(G, BASE)                                                   \
  {                                                                          \
    int lim = nseg - (BASE);                                                 \
    if (lim < 16) {                                                          \
      _Pragma("unroll")                                                      \
      for (int j = 0; j < 16; ++j)                                           \
        if (j >= lim) G[j] = 0.0f;                                           \
    }                                                                        \
    acc += (((G[0] + G[1]) + (G[2] + G[3])) + ((G[4] + G[5]) + (G[6] + G[7])))  \
         + (((G[8] + G[9]) + (G[10] + G[11])) + ((G[12] + G[13]) + (G[14] + G[15]))); \
  }

  int t = s;
  while (t < e) {
    int rem  = e - t;
    int nseg = rem < 64 ? rem : 64;
    int idxv = row[min(t + lane, e - 1)];   // up to 64 indices, one trip
    float gA[16], gB[16];
    ISSUE16(gA, 0)
    if (nseg > 16) ISSUE16(gB, 16)
    CONSUME16(gA, 0)
    if (nseg > 16) {
      if (nseg > 32) ISSUE16(gA, 32)
      CONSUME16(gB, 16)
      if (nseg > 32) {
        if (nseg > 48) ISSUE16(gB, 48)
        CONSUME16(gA, 32)
        if (nseg > 48) CONSUME16(gB, 48)
      }
    }
    t += 64;
  }
#undef ISSUE16
#undef CONSUME16

  int deg = e - s;
  float r = (deg > 0) ? (acc / (float)deg) : 0.0f;
  if (AGGBF) aggb[(size_t)wid * 64 + lane] = f2bf(r);
  else       aggf[(size_t)wid * 64 + lane] = r;
}

// K2: out[n] = b + [agg|x] @ W^T via bf16 MFMA 16x16x32.
// AGGBF: agg half comes from bf16 ws buffer; else f32 in-place from out.
template <bool BF, bool AGGBF>
__global__ __launch_bounds__(256) void sage_mm(
    const float* __restrict__ x, const unsigned short* __restrict__ xb,
    const unsigned short* __restrict__ aggb,
    const float* __restrict__ W, const float* __restrict__ b,
    float* __restrict__ out, int N) {
  __shared__ unsigned short ft[128][136];
  int tid = threadIdx.x;
  int l = tid & 63, w = tid >> 6;
  int colr = l & 15, kg = l >> 4;
  int n0 = blockIdx.x * 128;
  int rows = N - n0; if (rows > 128) rows = 128;

  bf16x8 bfrag[4][4];
  float bias[4];
  #pragma unroll
  for (int c = 0; c < 4; ++c) {
    bias[c] = b[c * 16 + colr];
    #pragma unroll
    for (int kq = 0; kq < 4; ++kq) {
      const float* wp = W + (size_t)(c * 16 + colr) * 128 + kq * 32 + kg * 8;
      float4 wa = *(const float4*)wp;
      float4 wb = *(const float4*)(wp + 4);
      union { unsigned short u[8]; bf16x8 v; } r;
      r.u[0] = f2bf(wa.x); r.u[1] = f2bf(wa.y); r.u[2] = f2bf(wa.z); r.u[3] = f2bf(wa.w);
      r.u[4] = f2bf(wb.x); r.u[5] = f2bf(wb.y); r.u[6] = f2bf(wb.z); r.u[7] = f2bf(wb.w);
      bfrag[c][kq] = r.v;
    }
  }

  const float* aggsrcf = out + (size_t)n0 * 64;
  #pragma unroll
  for (int it = 0; it < 4; ++it) {
    int flat = it * 2048 + tid * 8;
    int n = flat >> 6, k = flat & 63;
    { // agg half -> ft[n][0..63]
      uint4 v = make_uint4(0, 0, 0, 0);
      if (n < rows) {
        if (AGGBF) {
          v = *(const uint4*)(aggb + ((size_t)(n0 + n) * 64 + k));
        } else {
          const float4* p = (const float4*)(aggsrcf + (size_t)n * 64 + k);
          float4 a = p[0], bb = p[1];
          union { unsigned short u[8]; uint4 vv; } r;
          r.u[0] = f2bf(a.x);  r.u[1] = f2bf(a.y);  r.u[2] = f2bf(a.z);  r.u[3] = f2bf(a.w);
          r.u[4] = f2bf(bb.x); r.u[5] = f2bf(bb.y); r.u[6] = f2bf(bb.z); r.u[7] = f2bf(bb.w);
          v = r.vv;
        }
      }
      *(uint4*)&ft[n][k] = v;
    }
    { // x half -> ft[n][64..127]
      uint4 v = make_uint4(0, 0, 0, 0);
      if (n < rows) {
        if (BF) {
          v = *(const uint4*)(xb + ((size_t)(n0 + n) * 64 + k));
        } else {
          const float4* p = (const float4*)(x + (size_t)(n0 + n) * 64 + k);
          float4 a = p[0], bb = p[1];
          union { unsigned short u[8]; uint4 vv; } r;
          r.u[0] = f2bf(a.x);  r.u[1] = f2bf(a.y);  r.u[2] = f2bf(a.z);  r.u[3] = f2bf(a.w);
          r.u[4] = f2bf(bb.x); r.u[5] = f2bf(bb.y); r.u[6] = f2bf(bb.z); r.u[7] = f2bf(bb.w);
          v = r.vv;
        }
      }
      *(uint4*)&ft[n][64 + k] = v;
    }
  }
  __syncthreads();

  f32x4 acc[2][4];
  #pragma unroll
  for (int c = 0; c < 4; ++c) {
    acc[0][c] = (f32x4){bias[c], bias[c], bias[c], bias[c]};
    acc[1][c] = acc[0][c];
  }

  #pragma unroll
  for (int kq = 0; kq < 4; ++kq) {
    bf16x8 a0 = *(const bf16x8*)&ft[w * 32 + colr][kq * 32 + kg * 8];
    bf16x8 a1 = *(const bf16x8*)&ft[w * 32 + 16 + colr][kq * 32 + kg * 8];
    #pragma unroll
    for (int c = 0; c < 4; ++c) {
      acc[0][c] = __builtin_amdgcn_mfma_f32_16x16x32_bf16(a0, bfrag[c][kq], acc[0][c], 0, 0, 0);
      acc[1][c] = __builtin_amdgcn_mfma_f32_16x16x32_bf16(a1, bfrag[c][kq], acc[1][c], 0, 0, 0);
    }
  }

  #pragma unroll
  for (int m = 0; m < 2; ++m) {
    int nodeb = n0 + w * 32 + m * 16 + kg * 4;
    #pragma unroll
    for (int c = 0; c < 4; ++c) {
      #pragma unroll
      for (int r = 0; r < 4; ++r) {
        int node = nodeb + r;
        if (node < N) out[(size_t)node * 64 + c * 16 + colr] = acc[m][c][r];
      }
    }
  }
}

extern "C" void kernel_launch(void* const* d_in, const int* in_sizes, int n_in,
                              void* d_out, int out_size, void* d_ws, size_t ws_size,
                              hipStream_t stream) {
  const float* x      = (const float*)d_in[0];
  const int*   row    = (const int*)d_in[1];
  const int*   colptr = (const int*)d_in[2];
  const float* W      = (const float*)d_in[3];
  const float* b      = (const float*)d_in[4];
  float* out = (float*)d_out;

  int N = in_sizes[0] / 64;
  size_t nb_bf = (size_t)N * 64 * 2;   // bf16 x copy
  unsigned short* xb = (unsigned short*)d_ws;
  unsigned short* xa = (unsigned short*)((char*)d_ws + nb_bf);  // bf16 agg

  int total8 = N * 8;
  int nbc = (total8 + 255) / 256;
  int nba = (N + 3) / 4;
  int nbm = (N + 127) / 128;

  if (ws_size >= 2 * nb_bf) {
    cvt_bf16<<<nbc, 256, 0, stream>>>(x, xb, total8);
    agg_k<true, true><<<nba, 256, 0, stream>>>(x, xb, row, colptr, out, xa, N);
    sage_mm<true, true><<<nbm, 256, 0, stream>>>(x, xb, xa, W, b, out, N);
  } else if (ws_size >= nb_bf) {
    cvt_bf16<<<nbc, 256, 0, stream>>>(x, xb, total8);
    agg_k<true, false><<<nba, 256, 0, stream>>>(x, xb, row, colptr, out, xa, N);
    sage_mm<true, false><<<nbm, 256, 0, stream>>>(x, xb, xa, W, b, out, N);
  } else {
    agg_k<false, false><<<nba, 256, 0, stream>>>(x, xb, row, colptr, out, xa, N);
    sage_mm<false, false><<<nbm, 256, 0, stream>>>(x, xb, xa, W, b, out, N);
  }
}